// Round 22
// baseline (107.280 us; speedup 1.0000x reference)
//
#include <hip/hip_runtime.h>
#include <stdint.h>

#define IN_F   4096
#define OUT_F  11008
#define BATCH  8
#define CHUNK  256            // i-values per chunk (64 lanes * 4)
#define NCHUNK (IN_F/CHUNK)   // 16

__device__ __forceinline__ float qins_decode(int code, int sgn, float d0, float d1) {
    // |w| = exp2(d0 + code*d1); sign bit straight from the int32 sign (+1 / -1)
    const float e = __builtin_amdgcn_exp2f(fmaf((float)code, d1, d0));
    const uint32_t m = ((uint32_t)sgn) & 0x80000000u;
    return __uint_as_float(__float_as_uint(e) ^ m);
}

// Max-TLP streaming kernel: one output row per wave, 11008 waves = 43/CU.
// Deliberately NO pipeline, NO LDS, NO barriers: minimal register liveness
// (compiler sinks loads) -> <=64 VGPR -> 8 waves/SIMD resident. Latency is
// hidden by wave count (m13 copy-bench regime), not per-wave depth.
__global__ __launch_bounds__(256, 8)
void qins_linear_kernel(const float* __restrict__ x,
                        const int*   __restrict__ stored,
                        const int*   __restrict__ sign,
                        const float* __restrict__ log_min,
                        const float* __restrict__ log_max,
                        const float* __restrict__ bias,
                        float* __restrict__ out)
{
    const int lane = threadIdx.x & 63;
    const int wave = threadIdx.x >> 6;
    const int row  = blockIdx.x * 4 + wave;        // one row per wave

    const float lmin = log_min[0];
    const float lmax = log_max[0];
    const float L2E  = 1.44269504088896340736f;
    // log2(|w|) = d0 + code*d1
    const float d1 = -(lmax - lmin) * (L2E / 254.0f);
    const float d0 = (lmin + (lmax - lmin) * (255.0f / 254.0f)) * L2E;

    float acc[BATCH];
#pragma unroll
    for (int b = 0; b < BATCH; ++b) acc[b] = 0.0f;

    const int base = row * IN_F + lane * 4;        // < 2^26, 32-bit safe

#pragma unroll 1
    for (int i0 = 0; i0 < IN_F; i0 += CHUNK) {
        const int4 c = *reinterpret_cast<const int4*>(stored + base + i0);
        const int4 g = *reinterpret_cast<const int4*>(sign + base + i0);

        const float w0 = qins_decode(c.x, g.x, d0, d1);
        const float w1 = qins_decode(c.y, g.y, d0, d1);
        const float w2 = qins_decode(c.z, g.z, d0, d1);
        const float w3 = qins_decode(c.w, g.w, d0, d1);

#pragma unroll
        for (int b = 0; b < BATCH; ++b) {
            // same address across all waves of the CU -> L1-hot broadcast
            const float4 t = *reinterpret_cast<const float4*>(
                x + b * IN_F + i0 + lane * 4);
            float a = acc[b];
            a = fmaf(w0, t.x, a);
            a = fmaf(w1, t.y, a);
            a = fmaf(w2, t.z, a);
            a = fmaf(w3, t.w, a);
            acc[b] = a;
        }
    }

    // butterfly reduction of the 8 batch partials across the wave
#pragma unroll
    for (int b = 0; b < BATCH; ++b) {
        float v = acc[b];
#pragma unroll
        for (int s = 32; s >= 1; s >>= 1)
            v += __shfl_xor(v, s, 64);
        acc[b] = v;
    }

    if (lane == 0) {
        const float bv = bias[row];
#pragma unroll
        for (int b = 0; b < BATCH; ++b)
            out[(size_t)b * OUT_F + row] = acc[b] + bv;
    }
}

extern "C" void kernel_launch(void* const* d_in, const int* in_sizes, int n_in,
                              void* d_out, int out_size, void* d_ws, size_t ws_size,
                              hipStream_t stream)
{
    const float* x      = (const float*)d_in[0];
    const int*   stored = (const int*)d_in[1];
    const int*   sign   = (const int*)d_in[2];
    const float* lmin   = (const float*)d_in[3];
    const float* lmax   = (const float*)d_in[4];
    const float* bias   = (const float*)d_in[5];
    float* out = (float*)d_out;

    dim3 grid(OUT_F / 4), block(256);
    qins_linear_kernel<<<grid, block, 0, stream>>>(x, stored, sign, lmin, lmax, bias, out);
}